// Round 6
// baseline (544.185 us; speedup 1.0000x reference)
//
#include <hip/hip_runtime.h>

// ---------- tiny weight precompute: w012, P, Q (64 each) ----------
__global__ void smallvec_k(const float* __restrict__ W0, const float* __restrict__ b0,
                           const float* __restrict__ W1, const float* __restrict__ b1,
                           const float* __restrict__ W2a, float* __restrict__ SV) {
  __shared__ float w01[64], g[64];
  int j = threadIdx.x;
  float a = 0.f, bg = 0.f;
  for (int i = 0; i < 64; ++i) { float w = W1[i*64 + j]; a += W0[i]*w; bg += b0[i]*w; }
  w01[j] = a; g[j] = bg;
  __syncthreads();
  float w012 = 0.f, P = 0.f, Q = 0.f;
  for (int i = 0; i < 64; ++i) { float w = W2a[i*64 + j]; w012 += w01[i]*w; P += g[i]*w; Q += b1[i]*w; }
  SV[j] = w012; SV[64 + j] = P; SV[128 + j] = Q;
}

// ---------- zero int buffer ----------
__global__ void zero_k(int* __restrict__ p, int n) {
  int i = blockIdx.x * blockDim.x + threadIdx.x;
  if (i < n) p[i] = 0;
}

// ---------- histogram of dst ----------
__global__ void hist_k(const int* __restrict__ ei, int* __restrict__ cnt, int E) {
  int e = blockIdx.x * blockDim.x + threadIdx.x;
  if (e < E) atomicAdd(&cnt[ei[E + e]], 1);
}

// ---------- single-block exclusive scan: cnt(in ptr) -> ptr, cursor copy ----------
__global__ void scan_k(int* __restrict__ ptr, int* __restrict__ cur, int N) {
  __shared__ int sums[256];
  int t = threadIdx.x;
  int chunk = (N + 255) / 256;
  int lo = t * chunk, hi = lo + chunk; if (hi > N) hi = N; if (lo > N) lo = N;
  int s = 0;
  for (int i = lo; i < hi; ++i) s += ptr[i];
  sums[t] = s;
  __syncthreads();
  for (int off = 1; off < 256; off <<= 1) {
    int v = (t >= off) ? sums[t - off] : 0;
    __syncthreads();
    sums[t] += v;
    __syncthreads();
  }
  int run = sums[t] - s;
  for (int i = lo; i < hi; ++i) {
    int c = ptr[i];
    ptr[i] = run; cur[i] = run;
    run += c;
  }
  if (t == 255) ptr[N] = run;
}

// ---------- CSR fill: csr[cur[dst]++] = src ----------
__global__ void fill_k(const int* __restrict__ ei, int* __restrict__ cur,
                       int* __restrict__ csr, int E) {
  int e = blockIdx.x * blockDim.x + threadIdx.x;
  if (e >= E) return;
  int s = ei[e], d = ei[E + e];
  int pos = atomicAdd(&cur[d], 1);
  csr[pos] = s;
}

#define RED16(v) { v += __shfl_down(v, 8, 16); v += __shfl_down(v, 4, 16); \
                   v += __shfl_down(v, 2, 16); v += __shfl_down(v, 1, 16); }
#define NANFIX4(u) { u.x = (u.x!=u.x)?0.f:u.x; u.y = (u.y!=u.y)?0.f:u.y; \
                     u.z = (u.z!=u.z)?0.f:u.z; u.w = (u.w!=u.w)?0.f:u.w; }

// ---------- vectorized agg: 16 lanes per node, float4 row gathers ----------
// MODE 0: Fin=eig (nan->0), Dout = 1+deg
// MODE 1: Fin=B1, Din=D1, Dout=D2 (scalar gather fused)
// MODE 2: Fin=B2, no degree work
template<int MODE>
__global__ __launch_bounds__(256) void aggv_k(
    const int* __restrict__ ptr, const int* __restrict__ csr,
    const float* __restrict__ Fin, const float* __restrict__ Din,
    float* __restrict__ Fout, float* __restrict__ Dout, int N) {
  int g = blockIdx.x * 16 + (threadIdx.x >> 4);
  int t = threadIdx.x & 15;
  if (g >= N) return;
  int lo = ptr[g], hi = ptr[g + 1];
  float a0=0.f,a1=0.f,a2=0.f,a3=0.f,a4=0.f,a5=0.f,a6=0.f,a7=0.f,dd=0.f;
  for (int j = lo + t; j < hi; j += 16) {
    int s = csr[j];
    const float* r = Fin + (size_t)s * 8;
    float4 u0 = *(const float4*)r;
    float4 u1 = *(const float4*)(r + 4);
    if (MODE == 0) { NANFIX4(u0); NANFIX4(u1); }
    a0 += u0.x; a1 += u0.y; a2 += u0.z; a3 += u0.w;
    a4 += u1.x; a5 += u1.y; a6 += u1.z; a7 += u1.w;
    if (MODE == 1) dd += Din[s];
  }
  RED16(a0); RED16(a1); RED16(a2); RED16(a3);
  RED16(a4); RED16(a5); RED16(a6); RED16(a7);
  if (MODE == 1) RED16(dd);
  if (t == 0) {
    const float* r = Fin + (size_t)g * 8;
    float4 s0 = *(const float4*)r;
    float4 s1 = *(const float4*)(r + 4);
    if (MODE == 0) { NANFIX4(s0); NANFIX4(s1); }
    float4 o0 = { a0 + s0.x, a1 + s0.y, a2 + s0.z, a3 + s0.w };
    float4 o1 = { a4 + s1.x, a5 + s1.y, a6 + s1.z, a7 + s1.w };
    *(float4*)(Fout + (size_t)g * 8)     = o0;
    *(float4*)(Fout + (size_t)g * 8 + 4) = o1;
    if (MODE == 0) Dout[g] = 1.f + (float)(hi - lo);
    if (MODE == 1) Dout[g] = Din[g] + dd;
  }
}

// ---------- fused PE + rho: one wave per node (vbuf padded: no bank conflicts) ----------
__global__ __launch_bounds__(256) void pe_k(
    const float* __restrict__ B3, const float* __restrict__ D1, const float* __restrict__ D2,
    const float* __restrict__ SV, const float* __restrict__ b2a,
    const float* __restrict__ W2b, const float* __restrict__ b2b,
    const float* __restrict__ Wr1, const float* __restrict__ br1,
    const float* __restrict__ Wr2, const float* __restrict__ br2,
    float* __restrict__ out, int N) {
  __shared__ float vbuf[4][8][68];   // pad 64->68: bank = (4k+j)%32, distinct per k
  __shared__ float pebuf[4][128];
  __shared__ float zbuf[4][64];
  int wid  = threadIdx.x >> 6;
  int lane = threadIdx.x & 63;
  int n = blockIdx.x * 4 + wid;
  bool active = (n < N);
  float d1 = 0.f, d2 = 0.f;
  if (active) { d1 = D1[n]; d2 = D2[n]; }
  float w012 = SV[lane], P = SV[64 + lane], Q = SV[128 + lane];
  float Ej = d2 * P + d1 * Q + b2a[lane];
  if (active) {
    #pragma unroll
    for (int k = 0; k < 8; ++k) {
      float s = B3[(size_t)n*8 + k];
      float t = s * w012;
      vbuf[wid][k][lane] = fmaxf(t + Ej, 0.f) + fmaxf(Ej - t, 0.f);
    }
  }
  __syncthreads();
  if (active) {
    #pragma unroll
    for (int cc = 0; cc < 2; ++cc) {
      int c = lane + cc * 64;
      int k = c >> 4, o = c & 15;
      float acc = 2.f * b2b[o];
      #pragma unroll 8
      for (int j = 0; j < 64; ++j) acc += vbuf[wid][k][j] * W2b[j*16 + o];
      pebuf[wid][c] = acc;
    }
  }
  __syncthreads();
  float acc = br1[lane];
  if (active) {
    #pragma unroll 8
    for (int c = 0; c < 128; ++c) acc += pebuf[wid][c] * Wr1[c*64 + lane];
    zbuf[wid][lane] = fmaxf(acc, 0.f);
  }
  __syncthreads();
  if (active && lane < 16) {
    float acc2 = br2[lane];
    #pragma unroll 8
    for (int h = 0; h < 64; ++h) acc2 += zbuf[wid][h] * Wr2[h*16 + lane];
    out[(size_t)n*128 + 112 + lane] = acc2;
  }
}

// ---------- expand_x linear: out[:, 0:112] = x @ Wx + bx ----------
__global__ void x_k(const float* __restrict__ x, const float* __restrict__ Wx,
                    const float* __restrict__ bx, float* __restrict__ out, int total) {
  int idx = blockIdx.x * blockDim.x + threadIdx.x;
  if (idx >= total) return;
  int n = idx / 112, o = idx % 112;
  const float* xr = x + (size_t)n * 64;
  float acc = bx[o];
  #pragma unroll 8
  for (int i = 0; i < 64; ++i) acc += xr[i] * Wx[i*112 + o];
  out[(size_t)n*128 + o] = acc;
}

extern "C" void kernel_launch(void* const* d_in, const int* in_sizes, int n_in,
                              void* d_out, int out_size, void* d_ws, size_t ws_size,
                              hipStream_t stream) {
  const float* eig = (const float*)d_in[0];
  const float* x   = (const float*)d_in[1];
  const int*   ei  = (const int*)d_in[2];
  const float* W0  = (const float*)d_in[4];
  const float* b0  = (const float*)d_in[5];
  const float* W1  = (const float*)d_in[6];
  const float* b1  = (const float*)d_in[7];
  const float* W2a = (const float*)d_in[8];
  const float* b2a = (const float*)d_in[9];
  const float* W2b = (const float*)d_in[10];
  const float* b2b = (const float*)d_in[11];
  const float* Wr1 = (const float*)d_in[12];
  const float* br1 = (const float*)d_in[13];
  const float* Wr2 = (const float*)d_in[14];
  const float* br2 = (const float*)d_in[15];
  const float* Wx  = (const float*)d_in[16];
  const float* bx  = (const float*)d_in[17];
  float* out = (float*)d_out;

  int N = in_sizes[0] / 8;
  int E = in_sizes[2] / 2;

  int* ptr = (int*)d_ws;                 // N+1
  int* cur = ptr + (N + 1);              // N
  int* csr = cur + N;                    // E
  uintptr_t p = (uintptr_t)(csr + E);
  p = (p + 255) & ~(uintptr_t)255;       // 16B-align for float4 rows
  float* B1 = (float*)p;                 // N*8
  float* B2 = B1 + (size_t)N * 8;        // N*8
  float* B3 = B2 + (size_t)N * 8;        // N*8
  float* D1 = B3 + (size_t)N * 8;        // N
  float* D2 = D1 + N;                    // N
  float* SV = D2 + N;                    // 192

  int eblocks = (E + 255) / 256;
  int nblocks16 = (N + 15) / 16;

  zero_k<<<(N + 256) / 256, 256, 0, stream>>>(ptr, N + 1);
  hist_k<<<eblocks, 256, 0, stream>>>(ei, ptr, E);
  scan_k<<<1, 256, 0, stream>>>(ptr, cur, N);
  fill_k<<<eblocks, 256, 0, stream>>>(ei, cur, csr, E);

  smallvec_k<<<1, 64, 0, stream>>>(W0, b0, W1, b1, W2a, SV);

  aggv_k<0><<<nblocks16, 256, 0, stream>>>(ptr, csr, eig, nullptr, B1, D1, N);
  aggv_k<1><<<nblocks16, 256, 0, stream>>>(ptr, csr, B1, D1, B2, D2, N);
  aggv_k<2><<<nblocks16, 256, 0, stream>>>(ptr, csr, B2, nullptr, B3, nullptr, N);

  pe_k<<<(N + 3) / 4, 256, 0, stream>>>(B3, D1, D2, SV, b2a, W2b, b2b,
                                        Wr1, br1, Wr2, br2, out, N);
  x_k<<<(N * 112 + 255) / 256, 256, 0, stream>>>(x, Wx, bx, out, N * 112);
}

// Round 10
// 472.048 us; speedup vs baseline: 1.1528x; 1.1528x over previous
//
#include <hip/hip_runtime.h>

// ---------- zero int buffer ----------
__global__ void zero_k(int* __restrict__ p, int n) {
  int i = blockIdx.x * blockDim.x + threadIdx.x;
  if (i < n) p[i] = 0;
}

// ---------- histogram of dst ----------
__global__ void hist_k(const int* __restrict__ ei, int* __restrict__ cnt, int E) {
  int e = blockIdx.x * blockDim.x + threadIdx.x;
  if (e < E) atomicAdd(&cnt[ei[E + e]], 1);
}

// ---------- single-block scan (+ fused smallvec weight precompute) ----------
__global__ void scan_k(int* __restrict__ ptr, int* __restrict__ cur, int N,
                       const float* __restrict__ W0, const float* __restrict__ b0,
                       const float* __restrict__ W1, const float* __restrict__ b1,
                       const float* __restrict__ W2a, float* __restrict__ SV) {
  __shared__ int sums[256];
  __shared__ float w01[64], g[64];
  int t = threadIdx.x;
  int chunk = (N + 255) / 256;
  int lo = t * chunk, hi = lo + chunk; if (hi > N) hi = N; if (lo > N) lo = N;
  int s = 0;
  for (int i = lo; i < hi; ++i) s += ptr[i];
  sums[t] = s;
  // smallvec phase 1 (threads 0..63)
  if (t < 64) {
    float a = 0.f, bg = 0.f;
    for (int i = 0; i < 64; ++i) { float w = W1[i*64 + t]; a += W0[i]*w; bg += b0[i]*w; }
    w01[t] = a; g[t] = bg;
  }
  __syncthreads();
  for (int off = 1; off < 256; off <<= 1) {
    int v = (t >= off) ? sums[t - off] : 0;
    __syncthreads();
    sums[t] += v;
    __syncthreads();
  }
  int run = sums[t] - s;
  for (int i = lo; i < hi; ++i) {
    int c = ptr[i];
    ptr[i] = run; cur[i] = run;
    run += c;
  }
  if (t == 255) ptr[N] = run;
  // smallvec phase 2
  if (t < 64) {
    float w012 = 0.f, P = 0.f, Q = 0.f;
    for (int i = 0; i < 64; ++i) { float w = W2a[i*64 + t]; w012 += w01[i]*w; P += g[i]*w; Q += b1[i]*w; }
    SV[t] = w012; SV[64 + t] = P; SV[128 + t] = Q;
  }
}

// ---------- CSR fill: csr[cur[dst]++] = src ----------
__global__ void fill_k(const int* __restrict__ ei, int* __restrict__ cur,
                       int* __restrict__ csr, int E) {
  int e = blockIdx.x * blockDim.x + threadIdx.x;
  if (e >= E) return;
  int s = ei[e], d = ei[E + e];
  int pos = atomicAdd(&cur[d], 1);
  csr[pos] = s;
}

#define RED16(v) { v += __shfl_down(v, 8, 16); v += __shfl_down(v, 4, 16); \
                   v += __shfl_down(v, 2, 16); v += __shfl_down(v, 1, 16); }
#define NANFIX4(u) { u.x = (u.x!=u.x)?0.f:u.x; u.y = (u.y!=u.y)?0.f:u.y; \
                     u.z = (u.z!=u.z)?0.f:u.z; u.w = (u.w!=u.w)?0.f:u.w; }

// ---------- vectorized agg: 16 lanes per node, float4 row gathers ----------
template<int MODE>
__global__ __launch_bounds__(256) void aggv_k(
    const int* __restrict__ ptr, const int* __restrict__ csr,
    const float* __restrict__ Fin, const float* __restrict__ Din,
    float* __restrict__ Fout, float* __restrict__ Dout, int N) {
  int g = blockIdx.x * 16 + (threadIdx.x >> 4);
  int t = threadIdx.x & 15;
  if (g >= N) return;
  int lo = ptr[g], hi = ptr[g + 1];
  float a0=0.f,a1=0.f,a2=0.f,a3=0.f,a4=0.f,a5=0.f,a6=0.f,a7=0.f,dd=0.f;
  for (int j = lo + t; j < hi; j += 16) {
    int s = csr[j];
    const float* r = Fin + (size_t)s * 8;
    float4 u0 = *(const float4*)r;
    float4 u1 = *(const float4*)(r + 4);
    if (MODE == 0) { NANFIX4(u0); NANFIX4(u1); }
    a0 += u0.x; a1 += u0.y; a2 += u0.z; a3 += u0.w;
    a4 += u1.x; a5 += u1.y; a6 += u1.z; a7 += u1.w;
    if (MODE == 1) dd += Din[s];
  }
  RED16(a0); RED16(a1); RED16(a2); RED16(a3);
  RED16(a4); RED16(a5); RED16(a6); RED16(a7);
  if (MODE == 1) RED16(dd);
  if (t == 0) {
    const float* r = Fin + (size_t)g * 8;
    float4 s0 = *(const float4*)r;
    float4 s1 = *(const float4*)(r + 4);
    if (MODE == 0) { NANFIX4(s0); NANFIX4(s1); }
    float4 o0 = { a0 + s0.x, a1 + s0.y, a2 + s0.z, a3 + s0.w };
    float4 o1 = { a4 + s1.x, a5 + s1.y, a6 + s1.z, a7 + s1.w };
    *(float4*)(Fout + (size_t)g * 8)     = o0;
    *(float4*)(Fout + (size_t)g * 8 + 4) = o1;
    if (MODE == 0) Dout[g] = 1.f + (float)(hi - lo);
    if (MODE == 1) Dout[g] = Din[g] + dd;
  }
}

// ---------- fused PE + rho + expand_x: 4 waves/block, 4 nodes/wave ----------
// vbuf = relu(t+E)+relu(E-t) == max(2E, E+|t|, 0)
__global__ __launch_bounds__(256) void pe_k(
    const float* __restrict__ B3, const float* __restrict__ D1, const float* __restrict__ D2,
    const float* __restrict__ SV, const float* __restrict__ b2a,
    const float* __restrict__ W2b, const float* __restrict__ b2b,
    const float* __restrict__ Wr1, const float* __restrict__ br1,
    const float* __restrict__ Wr2, const float* __restrict__ br2,
    const float* __restrict__ x, const float* __restrict__ Wx,
    const float* __restrict__ bx,
    float* __restrict__ out, int N) {
  __shared__ float w2bT[16][68];    // [o][j], stride 68: 2-way max on reads (free)
  __shared__ float wr2T[16][68];    // [o][h]
  __shared__ float vbuf[4][8][68];  // per wave, one node at a time; rows 16B-aligned
  __shared__ float pebuf[16][128];  // [node-in-block][c]; reads broadcast -> no conflict
  __shared__ float zbuf[16][68];    // [node-in-block][h]
  int tid = threadIdx.x;
  int wid = tid >> 6, lane = tid & 63;

  // stage transposed small weights (both are [64][16])
  for (int u = tid; u < 1024; u += 256) {
    int j = u >> 4, o = u & 15;
    w2bT[o][j] = W2b[u];
    wr2T[o][j] = Wr2[u];
  }
  __syncthreads();   // the only block barrier

  int nb = blockIdx.x * 16 + wid * 4;   // first node of this wave
  float w012 = SV[lane], P = SV[64 + lane], Q = SV[128 + lane], b2aj = b2a[lane];
  int o16 = lane & 15, kk = lane >> 4;
  float bb2 = 2.f * b2b[o16];
  float br1h = br1[lane];

  // ---- per-node: vbuf (lane-j layout) -> pe (lane-(k,o) layout) ----
  #pragma unroll
  for (int m = 0; m < 4; ++m) {
    int n = nb + m;
    int nc = (n < N) ? n : 0;
    float d1 = D1[nc], d2 = D2[nc];
    float E = fmaf(d2, P, fmaf(d1, Q, b2aj));
    float E2 = E + E;
    const float* srow = B3 + (size_t)nc * 8;
    #pragma unroll
    for (int k = 0; k < 8; ++k) {
      float t = srow[k] * w012;
      vbuf[wid][k][lane] = fmaxf(fmaxf(E2, E + fabsf(t)), 0.f);
    }
    // intra-wave RAW on vbuf: in-order wave execution, no barrier needed
    float accA = bb2, accB = bb2;
    #pragma unroll
    for (int j4 = 0; j4 < 16; ++j4) {
      float4 w4 = *(const float4*)&w2bT[o16][4 * j4];
      float4 va = *(const float4*)&vbuf[wid][kk][4 * j4];
      float4 vb = *(const float4*)&vbuf[wid][kk + 4][4 * j4];
      accA += va.x * w4.x + va.y * w4.y + va.z * w4.z + va.w * w4.w;
      accB += vb.x * w4.x + vb.y * w4.y + vb.z * w4.z + vb.w * w4.w;
    }
    pebuf[wid * 4 + m][lane]      = accA;   // c = kk*16+o16 = lane
    pebuf[wid * 4 + m][lane + 64] = accB;   // c = (kk+4)*16+o16 = lane+64
  }

  // ---- rho1: lane = h, 4 nodes amortize the Wr1 loads ----
  float za[4] = { br1h, br1h, br1h, br1h };
  #pragma unroll 8
  for (int c4 = 0; c4 < 32; ++c4) {
    float w0 = Wr1[(4 * c4 + 0) * 64 + lane];
    float w1 = Wr1[(4 * c4 + 1) * 64 + lane];
    float w2 = Wr1[(4 * c4 + 2) * 64 + lane];
    float w3 = Wr1[(4 * c4 + 3) * 64 + lane];
    #pragma unroll
    for (int m = 0; m < 4; ++m) {
      float4 p = *(const float4*)&pebuf[wid * 4 + m][4 * c4];
      za[m] += p.x * w0 + p.y * w1 + p.z * w2 + p.w * w3;
    }
  }
  #pragma unroll
  for (int m = 0; m < 4; ++m) zbuf[wid * 4 + m][lane] = fmaxf(za[m], 0.f);

  // ---- rho2: lane -> (node kk, output o16) ----
  float acc2 = br2[o16];
  #pragma unroll
  for (int h4 = 0; h4 < 16; ++h4) {
    float4 zv = *(const float4*)&zbuf[wid * 4 + kk][4 * h4];
    float4 wv = *(const float4*)&wr2T[o16][4 * h4];
    acc2 += zv.x * wv.x + zv.y * wv.y + zv.z * wv.z + zv.w * wv.w;
  }
  {
    int nn = nb + kk;
    if (nn < N) out[(size_t)nn * 128 + 112 + o16] = acc2;
  }

  // ---- expand_x part: same 4 nodes; Wx loads amortize 4x ----
  float bxa = bx[lane];                               // o1 = lane (<112 always)
  float bxb = (lane < 48) ? bx[lane + 64] : 0.f;      // o2 = lane+64
  float xacc[4][2];
  #pragma unroll
  for (int m = 0; m < 4; ++m) { xacc[m][0] = bxa; xacc[m][1] = bxb; }
  #pragma unroll 4
  for (int i4 = 0; i4 < 16; ++i4) {
    float4 xv[4];
    #pragma unroll
    for (int m = 0; m < 4; ++m) {
      int nc = (nb + m < N) ? (nb + m) : 0;
      xv[m] = *(const float4*)(x + (size_t)nc * 64 + 4 * i4);
    }
    #pragma unroll
    for (int i = 0; i < 4; ++i) {
      int row = 4 * i4 + i;
      float wa = Wx[row * 112 + lane];
      float wb = (lane < 48) ? Wx[row * 112 + lane + 64] : 0.f;
      #pragma unroll
      for (int m = 0; m < 4; ++m) {
        float xs = ((const float*)&xv[m])[i];
        xacc[m][0] = fmaf(xs, wa, xacc[m][0]);
        xacc[m][1] = fmaf(xs, wb, xacc[m][1]);
      }
    }
  }
  #pragma unroll
  for (int m = 0; m < 4; ++m) {
    int n = nb + m;
    if (n < N) {
      out[(size_t)n * 128 + lane] = xacc[m][0];
      if (lane < 48) out[(size_t)n * 128 + lane + 64] = xacc[m][1];
    }
  }
}

extern "C" void kernel_launch(void* const* d_in, const int* in_sizes, int n_in,
                              void* d_out, int out_size, void* d_ws, size_t ws_size,
                              hipStream_t stream) {
  const float* eig = (const float*)d_in[0];
  const float* x   = (const float*)d_in[1];
  const int*   ei  = (const int*)d_in[2];
  const float* W0  = (const float*)d_in[4];
  const float* b0  = (const float*)d_in[5];
  const float* W1  = (const float*)d_in[6];
  const float* b1  = (const float*)d_in[7];
  const float* W2a = (const float*)d_in[8];
  const float* b2a = (const float*)d_in[9];
  const float* W2b = (const float*)d_in[10];
  const float* b2b = (const float*)d_in[11];
  const float* Wr1 = (const float*)d_in[12];
  const float* br1 = (const float*)d_in[13];
  const float* Wr2 = (const float*)d_in[14];
  const float* br2 = (const float*)d_in[15];
  const float* Wx  = (const float*)d_in[16];
  const float* bx  = (const float*)d_in[17];
  float* out = (float*)d_out;

  int N = in_sizes[0] / 8;
  int E = in_sizes[2] / 2;

  int* ptr = (int*)d_ws;                 // N+1
  int* cur = ptr + (N + 1);              // N
  int* csr = cur + N;                    // E
  uintptr_t p = (uintptr_t)(csr + E);
  p = (p + 255) & ~(uintptr_t)255;       // 16B-align for float4 rows
  float* B1 = (float*)p;                 // N*8
  float* B2 = B1 + (size_t)N * 8;        // N*8
  float* B3 = B2 + (size_t)N * 8;        // N*8
  float* D1 = B3 + (size_t)N * 8;        // N
  float* D2 = D1 + N;                    // N
  float* SV = D2 + N;                    // 192

  int eblocks = (E + 255) / 256;
  int nblocks16 = (N + 15) / 16;

  zero_k<<<(N + 256) / 256, 256, 0, stream>>>(ptr, N + 1);
  hist_k<<<eblocks, 256, 0, stream>>>(ei, ptr, E);
  scan_k<<<1, 256, 0, stream>>>(ptr, cur, N, W0, b0, W1, b1, W2a, SV);
  fill_k<<<eblocks, 256, 0, stream>>>(ei, cur, csr, E);

  aggv_k<0><<<nblocks16, 256, 0, stream>>>(ptr, csr, eig, nullptr, B1, D1, N);
  aggv_k<1><<<nblocks16, 256, 0, stream>>>(ptr, csr, B1, D1, B2, D2, N);
  aggv_k<2><<<nblocks16, 256, 0, stream>>>(ptr, csr, B2, nullptr, B3, nullptr, N);

  pe_k<<<nblocks16, 256, 0, stream>>>(B3, D1, D2, SV, b2a, W2b, b2b,
                                      Wr1, br1, Wr2, br2, x, Wx, bx, out, N);
}